// Round 1
// baseline (28.220 us; speedup 1.0000x reference)
//
#include <hip/hip_runtime.h>

#define SIM_T 0.8f

// Kernel 1: per (row, part) masked sum of exp(output[row, 1+k]) for k in the
// part's slice, keeping only k where cos[row, k] < SIM_T.
// grid = B * PARTS blocks, 256 threads.
__global__ __launch_bounds__(256) void pruner_partial(
    const float* __restrict__ out, const float* __restrict__ cs,
    float* __restrict__ ws, int K, int parts) {
  const int per_part = K / parts;
  const int row  = blockIdx.x / parts;
  const int part = blockIdx.x % parts;
  const int tid  = threadIdx.x;

  const float* crow = cs  + (size_t)row * K + (size_t)part * per_part;
  const float* orow = out + (size_t)row * (K + 1) + 1 + (size_t)part * per_part;

  float s0 = 0.f, s1 = 0.f, s2 = 0.f, s3 = 0.f;
  // float4 cos loads (aligned: row base and part offset are multiples of 4
  // elements); output is odd-strided so use 4 scalar loads (coalesced dwords).
  for (int k = tid * 4; k < per_part; k += 256 * 4) {
    float4 c = *reinterpret_cast<const float4*>(crow + k);
    float x0 = orow[k + 0];
    float x1 = orow[k + 1];
    float x2 = orow[k + 2];
    float x3 = orow[k + 3];
    s0 += (c.x < SIM_T) ? __expf(x0) : 0.0f;
    s1 += (c.y < SIM_T) ? __expf(x1) : 0.0f;
    s2 += (c.z < SIM_T) ? __expf(x2) : 0.0f;
    s3 += (c.w < SIM_T) ? __expf(x3) : 0.0f;
  }
  float s = (s0 + s1) + (s2 + s3);

  // wave64 shuffle reduce
  #pragma unroll
  for (int off = 32; off > 0; off >>= 1) s += __shfl_down(s, off, 64);

  __shared__ float lds[4];
  const int wave = tid >> 6;
  if ((tid & 63) == 0) lds[wave] = s;
  __syncthreads();
  if (tid == 0) ws[blockIdx.x] = (lds[0] + lds[1]) + (lds[2] + lds[3]);
}

// Kernel 2: one block of B threads. Thread i folds row i's partials with the
// always-kept positive logit, takes log, subtracts logit0, then the block
// reduces the mean into d_out[0].
__global__ __launch_bounds__(256) void pruner_final(
    const float* __restrict__ out, const float* __restrict__ ws,
    float* __restrict__ res, int K, int parts, int B) {
  const int i = threadIdx.x;  // row
  float loss = 0.0f;
  if (i < B) {
    float t = 0.0f;
    for (int p = 0; p < parts; ++p) t += ws[i * parts + p];
    const float o0 = out[(size_t)i * (K + 1)];
    t += __expf(o0);
    loss = logf(t) - o0;
  }
  #pragma unroll
  for (int off = 32; off > 0; off >>= 1) loss += __shfl_down(loss, off, 64);

  __shared__ float lds[4];
  if ((i & 63) == 0) lds[i >> 6] = loss;
  __syncthreads();
  if (i == 0) res[0] = ((lds[0] + lds[1]) + (lds[2] + lds[3])) / (float)B;
}

extern "C" void kernel_launch(void* const* d_in, const int* in_sizes, int n_in,
                              void* d_out, int out_size, void* d_ws, size_t ws_size,
                              hipStream_t stream) {
  const float* out = (const float*)d_in[0];   // [B, K+1] f32
  const float* cs  = (const float*)d_in[1];   // [B, K]   f32
  // d_in[2] (target) is unused by the loss.
  float* res = (float*)d_out;                 // scalar f32

  const int B = in_sizes[2];                  // 256
  const int K = in_sizes[1] / B;              // 65536
  const int PARTS = 8;                        // 8 blocks per row -> 2048 blocks

  float* ws = (float*)d_ws;                   // B*PARTS floats of scratch

  pruner_partial<<<B * PARTS, 256, 0, stream>>>(out, cs, ws, K, PARTS);
  pruner_final<<<1, 256, 0, stream>>>(out, ws, res, K, PARTS, B);
}

// Round 2
// 27.024 us; speedup vs baseline: 1.0442x; 1.0442x over previous
//
#include <hip/hip_runtime.h>

#define SIM_T 0.8f

// Kernel 1: per (row, part) masked sum of exp(output[row, 1+k]) over the
// part's slice, keeping only k where cos[row, k] < SIM_T.
// grid = B * PARTS blocks, 256 threads. per_part = K/PARTS = 8192.
// Each thread handles 32 elements in 2 iterations of 16, with all 20 memory
// ops of an iteration issued before any compute (raise MLP — we are
// latency-bound, not BW-bound: replays run fully from Infinity Cache).
__global__ __launch_bounds__(256) void pruner_partial(
    const float* __restrict__ out, const float* __restrict__ cs,
    float* __restrict__ ws, int K, int parts) {
  const int per_part = K / parts;          // 8192
  const int row  = blockIdx.x / parts;
  const int part = blockIdx.x % parts;
  const int tid  = threadIdx.x;

  const float* crow = cs  + (size_t)row * K + (size_t)part * per_part;
  const float* orow = out + (size_t)row * (K + 1) + 1 + (size_t)part * per_part;

  float a0 = 0.f, a1 = 0.f, a2 = 0.f, a3 = 0.f;

  // stride pattern: within an iteration, 4 strided groups of (tid*4 .. +3),
  // groups 1024 apart — identical coalescing to the R1 kernel, 4x the MLP.
  for (int kb = tid * 4; kb < per_part; kb += 4096) {
    // ---- issue all loads first ----
    float4 c0 = *reinterpret_cast<const float4*>(crow + kb);
    float4 c1 = *reinterpret_cast<const float4*>(crow + kb + 1024);
    float4 c2 = *reinterpret_cast<const float4*>(crow + kb + 2048);
    float4 c3 = *reinterpret_cast<const float4*>(crow + kb + 3072);
    float x00 = orow[kb +    0], x01 = orow[kb +    1], x02 = orow[kb +    2], x03 = orow[kb +    3];
    float x10 = orow[kb + 1024], x11 = orow[kb + 1025], x12 = orow[kb + 1026], x13 = orow[kb + 1027];
    float x20 = orow[kb + 2048], x21 = orow[kb + 2049], x22 = orow[kb + 2050], x23 = orow[kb + 2051];
    float x30 = orow[kb + 3072], x31 = orow[kb + 3073], x32 = orow[kb + 3074], x33 = orow[kb + 3075];
    // ---- then compute ----
    a0 += (c0.x < SIM_T) ? __expf(x00) : 0.f;
    a1 += (c0.y < SIM_T) ? __expf(x01) : 0.f;
    a2 += (c0.z < SIM_T) ? __expf(x02) : 0.f;
    a3 += (c0.w < SIM_T) ? __expf(x03) : 0.f;
    a0 += (c1.x < SIM_T) ? __expf(x10) : 0.f;
    a1 += (c1.y < SIM_T) ? __expf(x11) : 0.f;
    a2 += (c1.z < SIM_T) ? __expf(x12) : 0.f;
    a3 += (c1.w < SIM_T) ? __expf(x13) : 0.f;
    a0 += (c2.x < SIM_T) ? __expf(x20) : 0.f;
    a1 += (c2.y < SIM_T) ? __expf(x21) : 0.f;
    a2 += (c2.z < SIM_T) ? __expf(x22) : 0.f;
    a3 += (c2.w < SIM_T) ? __expf(x23) : 0.f;
    a0 += (c3.x < SIM_T) ? __expf(x30) : 0.f;
    a1 += (c3.y < SIM_T) ? __expf(x31) : 0.f;
    a2 += (c3.z < SIM_T) ? __expf(x32) : 0.f;
    a3 += (c3.w < SIM_T) ? __expf(x33) : 0.f;
  }
  float s = (a0 + a1) + (a2 + a3);

  // wave64 shuffle reduce
  #pragma unroll
  for (int off = 32; off > 0; off >>= 1) s += __shfl_down(s, off, 64);

  __shared__ float lds[4];
  const int wave = tid >> 6;
  if ((tid & 63) == 0) lds[wave] = s;
  __syncthreads();
  if (tid == 0) ws[blockIdx.x] = (lds[0] + lds[1]) + (lds[2] + lds[3]);
}

// Kernel 2: one block of B threads. Thread i folds row i's 8 partials with
// the always-kept positive logit, takes log, subtracts logit0, then the
// block reduces the mean into d_out[0].
__global__ __launch_bounds__(256) void pruner_final(
    const float* __restrict__ out, const float* __restrict__ ws,
    float* __restrict__ res, int K, int parts, int B) {
  const int i = threadIdx.x;  // row
  float loss = 0.0f;
  if (i < B) {
    const float4 p0 = *reinterpret_cast<const float4*>(ws + i * parts);
    const float4 p1 = *reinterpret_cast<const float4*>(ws + i * parts + 4);
    const float o0 = out[(size_t)i * (K + 1)];
    float t = ((p0.x + p0.y) + (p0.z + p0.w)) +
              ((p1.x + p1.y) + (p1.z + p1.w)) + __expf(o0);
    loss = logf(t) - o0;
  }
  #pragma unroll
  for (int off = 32; off > 0; off >>= 1) loss += __shfl_down(loss, off, 64);

  __shared__ float lds[4];
  if ((i & 63) == 0) lds[i >> 6] = loss;
  __syncthreads();
  if (i == 0) res[0] = ((lds[0] + lds[1]) + (lds[2] + lds[3])) / (float)B;
}

extern "C" void kernel_launch(void* const* d_in, const int* in_sizes, int n_in,
                              void* d_out, int out_size, void* d_ws, size_t ws_size,
                              hipStream_t stream) {
  const float* out = (const float*)d_in[0];   // [B, K+1] f32
  const float* cs  = (const float*)d_in[1];   // [B, K]   f32
  // d_in[2] (target) is unused by the loss.
  float* res = (float*)d_out;                 // scalar f32

  const int B = in_sizes[2];                  // 256
  const int K = in_sizes[1] / B;              // 65536
  const int PARTS = 8;                        // 8 blocks/row -> 2048 blocks = 8/CU

  float* ws = (float*)d_ws;                   // B*PARTS floats of scratch

  pruner_partial<<<B * PARTS, 256, 0, stream>>>(out, cs, ws, K, PARTS);
  pruner_final<<<1, 256, 0, stream>>>(out, ws, res, K, PARTS, B);
}